// Round 7
// baseline (213.441 us; speedup 1.0000x reference)
//
#include <hip/hip_runtime.h>
#include <hip/hip_bf16.h>
#include <cstdint>
#include <cstddef>
#include <cmath>

#define B_  2
#define T_  2048
#define C_  1024
#define NH_ 16
#define HD_ 64

typedef __bf16 bf16;
typedef bf16  bf16x8 __attribute__((ext_vector_type(8)));
typedef bf16  bf16x4 __attribute__((ext_vector_type(4)));
typedef float f32x4  __attribute__((ext_vector_type(4)));
typedef float f32x16 __attribute__((ext_vector_type(16)));

#define MFMA16(a, b, c) __builtin_amdgcn_mfma_f32_16x16x32_bf16((a), (b), (c), 0, 0, 0)
#define MFMA32(a, b, c) __builtin_amdgcn_mfma_f32_32x32x16_bf16((a), (b), (c), 0, 0, 0)

// Async 16B global->LDS; LDS dest = wave-uniform base + lane*16.
__device__ __forceinline__ void gld_lds16(const bf16* g, bf16* lds_base_uniform) {
    __builtin_amdgcn_global_load_lds(
        (const __attribute__((address_space(1))) uint32_t*)g,
        (__attribute__((address_space(3))) uint32_t*)lds_base_uniform,
        16, 0, 0);
}

// ---------------------------------------------------------------------------
// Fused casts: blocks 0..4095 -> x (4 Mi elems); 4096..5119 -> all 4 weights.
// Wq is pre-scaled by 0.125*log2(e) so attention scores are exp2-ready.
// ---------------------------------------------------------------------------
__global__ __launch_bounds__(256) void cast_all(const float* __restrict__ x,
                                                const float* __restrict__ Wq,
                                                const float* __restrict__ Wk,
                                                const float* __restrict__ Wv,
                                                const float* __restrict__ Wo,
                                                bf16* __restrict__ xb,
                                                bf16* __restrict__ Wqk,
                                                bf16* __restrict__ Wvb,
                                                bf16* __restrict__ Wob) {
    const int bid = blockIdx.x;
    if (bid < 4096) {
        const int i = bid * 256 + threadIdx.x;
        float4 v = ((const float4*)x)[i];
        ((bf16x4*)xb)[i] = bf16x4{ (bf16)v.x, (bf16)v.y, (bf16)v.z, (bf16)v.w };
    } else {
        const float C1 = 0.1803368801111f;   // 0.125 * log2(e)
        const int i = (bid - 4096) * 256 + threadIdx.x;
        const int nw4 = C_ * C_ / 4;
        float4 q = ((const float4*)Wq)[i];
        float4 k = ((const float4*)Wk)[i];
        float4 v = ((const float4*)Wv)[i];
        float4 o = ((const float4*)Wo)[i];
        ((bf16x4*)Wqk)[i]       = bf16x4{ (bf16)(q.x * C1), (bf16)(q.y * C1),
                                          (bf16)(q.z * C1), (bf16)(q.w * C1) };
        ((bf16x4*)Wqk)[nw4 + i] = bf16x4{ (bf16)k.x, (bf16)k.y, (bf16)k.z, (bf16)k.w };
        ((bf16x4*)Wvb)[i]       = bf16x4{ (bf16)v.x, (bf16)v.y, (bf16)v.z, (bf16)v.w };
        ((bf16x4*)Wob)[i]       = bf16x4{ (bf16)o.x, (bf16)o.y, (bf16)o.z, (bf16)o.w };
    }
}

// ---------------------------------------------------------------------------
// 128x128 GEMM tile device fn (NT), depth-2 pipeline: 3 LDS buffers, stage
// tile k+2 while computing tile k, counted s_waitcnt vmcnt(4) (tile k+1's 4
// loads are the oldest; newest 4 may stay in flight) + RAW s_barrier (no
// __syncthreads -- that would emit vmcnt(0) and defeat the pipeline).
// Buffer-reuse safety: stage(k+2) targets the buffer computed at k-1, whose
// ds_reads completed before the end-of-(k-1) barrier.
// As/Bs: [3][128*32] each (48 KB total) -> 3 blocks/CU, grid 768 = exact.
// ---------------------------------------------------------------------------
__device__ __forceinline__ void gemm_tile(bf16* As, bf16* Bs,
                                          const bf16* __restrict__ A,
                                          const bf16* __restrict__ W,
                                          bf16* __restrict__ Y,
                                          int N, int K, int m0, int n0) {
    const int tid  = threadIdx.x;
    const int lane = tid & 63;
    const int w    = tid >> 6;
    const int ml   = lane & 15;
    const int quad = lane >> 4;
    const int wm   = (w >> 1) * 64;
    const int wn   = (w & 1) * 64;
    const int sr   = lane >> 2;
    const int sc   = lane & 3;

    f32x4 acc[4][4] = {};

    auto stage = [&](int k0, int buf) {
#pragma unroll
        for (int ei = 0; ei < 2; ++ei) {
            const int e = w * 2 + ei;
            gld_lds16(A + (size_t)(m0 + e * 16 + sr) * K + k0 + sc * 8, &As[buf * 4096 + e * 512]);
            gld_lds16(W + (size_t)(n0 + e * 16 + sr) * K + k0 + sc * 8, &Bs[buf * 4096 + e * 512]);
        }
    };

    stage(0, 0);
    stage(32, 1);
    asm volatile("s_waitcnt vmcnt(4)" ::: "memory");   // tile 0's 4 loads done
    __builtin_amdgcn_s_barrier();

    int buf = 0;
    for (int k0 = 0; k0 < K; k0 += 32) {
        const int bnext = (buf == 2) ? 0 : buf + 1;
        const int bpre  = (bnext == 2) ? 0 : bnext + 1;
        const int kpre  = k0 + 64;
        if (kpre < K) stage(kpre, bpre);

        bf16x8 af[4], bfr[4];
#pragma unroll
        for (int t = 0; t < 4; ++t) {
            af[t]  = *(const bf16x8*)&As[buf * 4096 + (wm + t * 16 + ml) * 32 + quad * 8];
            bfr[t] = *(const bf16x8*)&Bs[buf * 4096 + (wn + t * 16 + ml) * 32 + quad * 8];
        }
#pragma unroll
        for (int mt = 0; mt < 4; ++mt)
#pragma unroll
            for (int nt = 0; nt < 4; ++nt)
                acc[mt][nt] = MFMA16(af[mt], bfr[nt], acc[mt][nt]);

        if (k0 + 32 < K) {
            if (kpre < K) { asm volatile("s_waitcnt vmcnt(4)" ::: "memory"); }
            else          { asm volatile("s_waitcnt vmcnt(0)" ::: "memory"); }
            __builtin_amdgcn_s_barrier();
        }
        buf = bnext;
    }

#pragma unroll
    for (int mt = 0; mt < 4; ++mt)
#pragma unroll
        for (int nt = 0; nt < 4; ++nt)
#pragma unroll
            for (int r = 0; r < 4; ++r) {
                const int row = m0 + wm + mt * 16 + quad * 4 + r;
                const int col = n0 + wn + nt * 16 + ml;
                Y[(size_t)row * N + col] = (bf16)acc[mt][nt][r];
            }
}

// Fused projections: blocks 0..511 -> QK = x @ Wqk^T   [4096 x 2048]
//                    blocks 512..767 -> V^T = Wv @ x^T [1024 x 4096]
__global__ __launch_bounds__(256) void proj_fused(const bf16* __restrict__ xb,
                                                  const bf16* __restrict__ Wqk,
                                                  const bf16* __restrict__ Wvb,
                                                  bf16* __restrict__ QKb,
                                                  bf16* __restrict__ VtT) {
    __shared__ __align__(16) bf16 As[3][128 * 32];
    __shared__ __align__(16) bf16 Bs[3][128 * 32];
    const int bid = blockIdx.x;
    if (bid < 512) {
        gemm_tile(&As[0][0], &Bs[0][0], xb, Wqk, QKb, 2048, 1024, (bid >> 4) * 128, (bid & 15) * 128);
    } else {
        const int b2 = bid - 512;
        gemm_tile(&As[0][0], &Bs[0][0], Wvb, xb, VtT, 4096, 1024, (b2 >> 5) * 128, (b2 & 31) * 128);
    }
}

// ---------------------------------------------------------------------------
// Output GEMM: out[4096,1024] = Ab @ Wo^T, fp32 out. 64x128 tile -> 512 blocks.
// Depth-2 pipeline, 3 buffers, counted vmcnt(3) (3 loads/tile/wave).
// LDS = 3*(4K + 8K) = 36 KB -> 4 blocks/CU.
// ---------------------------------------------------------------------------
__global__ __launch_bounds__(256) void gemm_wo(const bf16* __restrict__ A,
                                               const bf16* __restrict__ W,
                                               float* __restrict__ Y) {
    __shared__ __align__(16) bf16 As[3][64 * 32];
    __shared__ __align__(16) bf16 Bs[3][128 * 32];
    const int tid  = threadIdx.x;
    const int lane = tid & 63;
    const int w    = tid >> 6;
    const int ml   = lane & 15;
    const int quad = lane >> 4;
    const int wm   = (w >> 1) * 32;
    const int wn   = (w & 1) * 64;
    const int m0   = blockIdx.y * 64;
    const int n0   = blockIdx.x * 128;
    const int sr   = lane >> 2;
    const int sc   = lane & 3;

    f32x4 acc[2][4] = {};

    auto stage = [&](int k0, int buf) {
        gld_lds16(A + (size_t)(m0 + w * 16 + sr) * 1024 + k0 + sc * 8, &As[buf][w * 512]);
#pragma unroll
        for (int ei = 0; ei < 2; ++ei) {
            const int e = w * 2 + ei;
            gld_lds16(W + (size_t)(n0 + e * 16 + sr) * 1024 + k0 + sc * 8, &Bs[buf][e * 512]);
        }
    };

    stage(0, 0);
    stage(32, 1);
    asm volatile("s_waitcnt vmcnt(3)" ::: "memory");   // tile 0's 3 loads done
    __builtin_amdgcn_s_barrier();

    int buf = 0;
    for (int k0 = 0; k0 < 1024; k0 += 32) {
        const int bnext = (buf == 2) ? 0 : buf + 1;
        const int bpre  = (bnext == 2) ? 0 : bnext + 1;
        const int kpre  = k0 + 64;
        if (kpre < 1024) stage(kpre, bpre);

        bf16x8 af[2], bfr[4];
#pragma unroll
        for (int t = 0; t < 2; ++t)
            af[t] = *(const bf16x8*)&As[buf][(wm + t * 16 + ml) * 32 + quad * 8];
#pragma unroll
        for (int t = 0; t < 4; ++t)
            bfr[t] = *(const bf16x8*)&Bs[buf][(wn + t * 16 + ml) * 32 + quad * 8];
#pragma unroll
        for (int mt = 0; mt < 2; ++mt)
#pragma unroll
            for (int nt = 0; nt < 4; ++nt)
                acc[mt][nt] = MFMA16(af[mt], bfr[nt], acc[mt][nt]);

        if (k0 + 32 < 1024) {
            if (kpre < 1024) { asm volatile("s_waitcnt vmcnt(3)" ::: "memory"); }
            else             { asm volatile("s_waitcnt vmcnt(0)" ::: "memory"); }
            __builtin_amdgcn_s_barrier();
        }
        buf = bnext;
    }

#pragma unroll
    for (int mt = 0; mt < 2; ++mt)
#pragma unroll
        for (int nt = 0; nt < 4; ++nt)
#pragma unroll
            for (int r = 0; r < 4; ++r) {
                const int row = m0 + wm + mt * 16 + quad * 4 + r;
                const int col = n0 + wn + nt * 16 + ml;
                Y[(size_t)row * 1024 + col] = acc[mt][nt][r];
            }
}

// ---------------------------------------------------------------------------
// Flash attention v12: swapped QK^T (S^T = mfma(K,Q)) keeps P lane-local;
// P->PV A-frags built in-register via v_cvt_pk_bf16_f32 + v_permlane32_swap
// (T12). VALU L-sum. LDS 32KB. __launch_bounds__(256,4) (R4's (256,5)
// caused scratch spill).
// ---------------------------------------------------------------------------
__global__ __launch_bounds__(256, 4) void attn_mfma(const bf16* __restrict__ QKb,
                                                    const bf16* __restrict__ VtT,
                                                    bf16* __restrict__ Pbuf,
                                                    float* __restrict__ Lbuf) {
    const int bid = blockIdx.x;
    const int hb  = bid & 31;
    const int s   = 39 - (bid >> 5);      // slot, heavy (high tile) first
    int it, chunk;
    if (s < 4)       { it = s;                  chunk = 0; }
    else if (s < 12) { it = 4 + ((s - 4) >> 1); chunk = (s - 4) & 1; }
    else if (s < 24) { it = 8 + (s - 12) / 3;   chunk = (s - 12) % 3; }
    else             { it = 12 + ((s - 24) >> 2); chunk = (s - 24) & 3; }
    const int h = hb >> 1, b = hb & 1;

    const int tid  = threadIdx.x;
    const int lane = tid & 63;
    const int w    = tid >> 6;
    const int keyl = lane & 31;
    const int hi   = lane >> 5;

    __shared__ __align__(16) bf16 Ks[2][4096];
    __shared__ __align__(16) bf16 Vs[2][4096];

    const bf16* Qbase = QKb + (size_t)b * T_ * 2048 + (size_t)h * HD_;
    const bf16* Kbase = Qbase + 1024;
    const bf16* Vbase = VtT + (size_t)h * HD_ * 4096 + (size_t)b * T_;

    // Q rows for this wave; B-frag for swapped QK^T: col(q)=lane&31, k=8*hi+e
    const int qrow = it * 128 + w * 32 + keyl;
    bf16x8 qf[4];
#pragma unroll
    for (int dc = 0; dc < 4; ++dc)
        qf[dc] = *(const bf16x8*)(Qbase + (size_t)qrow * 2048 + dc * 16 + hi * 8);

    f32x16 o_acc[2] = {};
    float l_run = 0.f;

    const int ktbase  = chunk * 8;
    const int nrounds = min(8, 2 * it + 2 - ktbase);

    // Stage K[64 keys][64 d] and V^T[64 d][64 keys] as 128B rows with 16B
    // granules swizzled: granule g holds data-granule g ^ (row&7). Staged by
    // pre-swizzling the global source (LDS write is linear in lane order).
    auto stageKV = [&](int ktg, int buf) {
        const int k0 = ktg * 64;
#pragma unroll
        for (int ei = 0; ei < 2; ++ei) {
            const int e  = w * 2 + ei;              // 0..7 -> 8 rows per e
            const int rr = e * 8 + (lane >> 3);     // row (key for K, d for V)
            const int g  = (lane & 7) ^ (lane >> 3);// swizzled data granule
            gld_lds16(Kbase + (size_t)(k0 + rr) * 2048 + g * 8, &Ks[buf][e * 512]);
            gld_lds16(Vbase + (size_t)rr * 4096 + k0 + g * 8, &Vs[buf][e * 512]);
        }
    };

    auto round = [&](int cur, int ktg) {
        const int k0 = ktg * 64;
        const bool domask = (k0 + 63) > (it * 128 + w * 32);
        const int qg = it * 128 + w * 32 + keyl;
#pragma unroll
        for (int kh = 0; kh < 2; ++kh) {
            f32x16 sacc = {};
#pragma unroll
            for (int dc = 0; dc < 4; ++dc) {
                // A-frag of K: row(key)=lane&31, k(d)=8*hi+e within chunk dc
                bf16x8 kf = *(const bf16x8*)&Ks[cur][(kh * 32 + keyl) * 64 +
                                                     (((dc << 1) | hi) ^ (keyl & 7)) * 8];
                sacc = MFMA32(kf, qf[dc], sacc);
            }
#pragma unroll
            for (int c = 0; c < 2; ++c) {
                float p[8];
#pragma unroll
                for (int r8 = 0; r8 < 8; ++r8) {
                    float arg = sacc[8 * c + r8];
                    if (domask) {
                        const int kg = k0 + kh * 32 + 16 * c + 8 * (r8 >> 2) + 4 * hi + (r8 & 3);
                        if (kg > qg) arg = -1e30f;
                    }
                    p[r8] = __builtin_amdgcn_exp2f(arg);
                }
                l_run += ((p[0] + p[1]) + (p[2] + p[3])) + ((p[4] + p[5]) + (p[6] + p[7]));
                uint32_t a0, a1, b0, b1;
                asm("v_cvt_pk_bf16_f32 %0, %1, %2" : "=v"(a0) : "v"(p[0]), "v"(p[1]));
                asm("v_cvt_pk_bf16_f32 %0, %1, %2" : "=v"(a1) : "v"(p[2]), "v"(p[3]));
                asm("v_cvt_pk_bf16_f32 %0, %1, %2" : "=v"(b0) : "v"(p[4]), "v"(p[5]));
                asm("v_cvt_pk_bf16_f32 %0, %1, %2" : "=v"(b1) : "v"(p[6]), "v"(p[7]));
                asm("v_permlane32_swap_b32 %0, %1" : "+v"(a0), "+v"(b0));
                asm("v_permlane32_swap_b32 %0, %1" : "+v"(a1), "+v"(b1));
                union { uint32_t d[4]; bf16x8 v; } pa;
                pa.d[0] = a0; pa.d[1] = a1; pa.d[2] = b0; pa.d[3] = b1;
                const int kc = 2 * kh + c;
#pragma unroll
                for (int dh = 0; dh < 2; ++dh) {
                    // B-frag of V: col(d)=lane&31, k(key)=8*hi+e within chunk kc
                    bf16x8 vf = *(const bf16x8*)&Vs[cur][(dh * 32 + keyl) * 64 +
                                                         (((kc << 1) | hi) ^ (keyl & 7)) * 8];
                    o_acc[dh] = MFMA32(pa.v, vf, o_acc[dh]);
                }
            }
        }
    };

    stageKV(ktbase, 0);
    asm volatile("s_waitcnt vmcnt(0)" ::: "memory");
    asm volatile("s_barrier" ::: "memory");

    for (int j = 0; j < nrounds; ++j) {
        const int cur = j & 1;
        const int ktg = ktbase + j;
        if (j + 1 < nrounds) stageKV(ktg + 1, cur ^ 1);
        round(cur, ktg);
        if (j + 1 < nrounds) {
            asm volatile("s_waitcnt vmcnt(0)" ::: "memory");
            asm volatile("s_barrier" ::: "memory");
        }
    }

    const int slotIdx = hb * 40 + s;
    bf16* pb = Pbuf + (size_t)slotIdx * 8192;
#pragma unroll
    for (int dh = 0; dh < 2; ++dh)
#pragma unroll
        for (int r = 0; r < 16; ++r) {
            const int qloc = w * 32 + (r & 3) + 8 * (r >> 2) + 4 * hi;
            pb[qloc * 64 + dh * 32 + keyl] = (bf16)o_acc[dh][r];
        }
    const float l_tot = l_run + __shfl_xor(l_run, 32);
    if (hi == 0)
        Lbuf[slotIdx * 128 + w * 32 + keyl] = l_tot;
}

// ---------------------------------------------------------------------------
// Merge partials: grid 512 = (tile, h, b); sum <=4 chunks of 128x64,
// normalize, write Ab.
// ---------------------------------------------------------------------------
__global__ __launch_bounds__(256) void attn_merge(const bf16* __restrict__ Pbuf,
                                                  const float* __restrict__ Lbuf,
                                                  bf16* __restrict__ Ab) {
    const int gid = blockIdx.x;
    const int it  = gid >> 5;
    const int hb  = gid & 31;
    const int h = hb >> 1, b = hb & 1;
    int s0;
    if (it < 4)       s0 = it;
    else if (it < 8)  s0 = 4 + (it - 4) * 2;
    else if (it < 12) s0 = 12 + (it - 8) * 3;
    else              s0 = 24 + (it - 12) * 4;
    const int nch = (2 * it + 9) >> 3;

    const int tid = threadIdx.x;
    const int row = tid >> 1;            // 0..127
    const int cg  = (tid & 1) * 32;      // 0 or 32

    float acc[32] = {};
    float lsum = 0.f;
    for (int c = 0; c < nch; ++c) {
        const int slot = hb * 40 + s0 + c;
        lsum += Lbuf[slot * 128 + row];
        const bf16* pb = Pbuf + (size_t)slot * 8192 + row * 64 + cg;
#pragma unroll
        for (int g = 0; g < 4; ++g) {
            bf16x8 v = *(const bf16x8*)(pb + g * 8);
#pragma unroll
            for (int j = 0; j < 8; ++j) acc[g * 8 + j] += (float)v[j];
        }
    }
    const float rcl = 1.0f / lsum;
    bf16* dst = Ab + (size_t)(b * T_ + it * 128 + row) * 1024 + h * 64 + cg;
#pragma unroll
    for (int g = 0; g < 4; ++g) {
        bf16x8 o;
#pragma unroll
        for (int j = 0; j < 8; ++j) o[j] = (bf16)(acc[g * 8 + j] * rcl);
        *(bf16x8*)(dst + g * 8) = o;
    }
}

// ---------------------------------------------------------------------------
extern "C" void kernel_launch(void* const* d_in, const int* in_sizes, int n_in,
                              void* d_out, int out_size, void* d_ws, size_t ws_size,
                              hipStream_t stream) {
    const float* x  = (const float*)d_in[0];
    const float* Wq = (const float*)d_in[1];
    const float* Wk = (const float*)d_in[2];
    const float* Wv = (const float*)d_in[3];
    const float* Wo = (const float*)d_in[4];
    float* out = (float*)d_out;

    const size_t n_x = (size_t)B_ * T_ * C_;  // 4 Mi
    const size_t n_w = (size_t)C_ * C_;       // 1 Mi

    bf16* xb   = (bf16*)d_ws;        // 8 MB
    bf16* Wqk  = xb + n_x;           // 4 MB ([Wq; Wk])
    bf16* Wvb  = Wqk + 2 * n_w;      // 2 MB
    bf16* Wob  = Wvb + n_w;          // 2 MB
    bf16* QKb  = Wob + n_w;          // 16 MB (4096 x 2048)
    bf16* VtT  = QKb + 2 * n_x;      // 8 MB (1024 x 4096)
    bf16* Ab   = VtT + n_x;          // 8 MB (4096 x 1024)
    bf16* Pbuf = Ab + n_x;           // 21 MB (1280 x 128 x 64)
    float* Lbuf = (float*)(Pbuf + (size_t)1280 * 8192);  // 0.66 MB

    cast_all<<<5120, 256, 0, stream>>>(x, Wq, Wk, Wv, Wo, xb, Wqk, Wvb, Wob);

    proj_fused<<<768, 256, 0, stream>>>(xb, Wqk, Wvb, QKb, VtT);

    attn_mfma<<<1280, 256, 0, stream>>>(QKb, VtT, Pbuf, Lbuf);
    attn_merge<<<512, 256, 0, stream>>>(Pbuf, Lbuf, Ab);

    gemm_wo<<<dim3(1024 / 128, 4096 / 64), 256, 0, stream>>>(Ab, Wob, out);
}

// Round 8
// 175.660 us; speedup vs baseline: 1.2151x; 1.2151x over previous
//
#include <hip/hip_runtime.h>
#include <hip/hip_bf16.h>
#include <cstdint>
#include <cstddef>
#include <cmath>

#define B_  2
#define T_  2048
#define C_  1024
#define NH_ 16
#define HD_ 64

typedef __bf16 bf16;
typedef bf16  bf16x8 __attribute__((ext_vector_type(8)));
typedef bf16  bf16x4 __attribute__((ext_vector_type(4)));
typedef float f32x4  __attribute__((ext_vector_type(4)));
typedef float f32x16 __attribute__((ext_vector_type(16)));

#define MFMA16(a, b, c) __builtin_amdgcn_mfma_f32_16x16x32_bf16((a), (b), (c), 0, 0, 0)
#define MFMA32(a, b, c) __builtin_amdgcn_mfma_f32_32x32x16_bf16((a), (b), (c), 0, 0, 0)

// Async 16B global->LDS; LDS dest = wave-uniform base + lane*16.
__device__ __forceinline__ void gld_lds16(const bf16* g, bf16* lds_base_uniform) {
    __builtin_amdgcn_global_load_lds(
        (const __attribute__((address_space(1))) uint32_t*)g,
        (__attribute__((address_space(3))) uint32_t*)lds_base_uniform,
        16, 0, 0);
}

// ---------------------------------------------------------------------------
// Fused casts: blocks 0..4095 -> x (4 Mi elems); 4096..5119 -> all 4 weights.
// Wq is pre-scaled by 0.125*log2(e) so attention scores are exp2-ready.
// ---------------------------------------------------------------------------
__global__ __launch_bounds__(256) void cast_all(const float* __restrict__ x,
                                                const float* __restrict__ Wq,
                                                const float* __restrict__ Wk,
                                                const float* __restrict__ Wv,
                                                const float* __restrict__ Wo,
                                                bf16* __restrict__ xb,
                                                bf16* __restrict__ Wqk,
                                                bf16* __restrict__ Wvb,
                                                bf16* __restrict__ Wob) {
    const int bid = blockIdx.x;
    if (bid < 4096) {
        const int i = bid * 256 + threadIdx.x;
        float4 v = ((const float4*)x)[i];
        ((bf16x4*)xb)[i] = bf16x4{ (bf16)v.x, (bf16)v.y, (bf16)v.z, (bf16)v.w };
    } else {
        const float C1 = 0.1803368801111f;   // 0.125 * log2(e)
        const int i = (bid - 4096) * 256 + threadIdx.x;
        const int nw4 = C_ * C_ / 4;
        float4 q = ((const float4*)Wq)[i];
        float4 k = ((const float4*)Wk)[i];
        float4 v = ((const float4*)Wv)[i];
        float4 o = ((const float4*)Wo)[i];
        ((bf16x4*)Wqk)[i]       = bf16x4{ (bf16)(q.x * C1), (bf16)(q.y * C1),
                                          (bf16)(q.z * C1), (bf16)(q.w * C1) };
        ((bf16x4*)Wqk)[nw4 + i] = bf16x4{ (bf16)k.x, (bf16)k.y, (bf16)k.z, (bf16)k.w };
        ((bf16x4*)Wvb)[i]       = bf16x4{ (bf16)v.x, (bf16)v.y, (bf16)v.z, (bf16)v.w };
        ((bf16x4*)Wob)[i]       = bf16x4{ (bf16)o.x, (bf16)o.y, (bf16)o.z, (bf16)o.w };
    }
}

// ---------------------------------------------------------------------------
// 128x128 GEMM tile device fn (NT), R5 single-buffer structure (measured
// best; R6 1-deep dbuf neutral, R7 counted-vmcnt depth-2 regressed -45%).
// ---------------------------------------------------------------------------
__device__ __forceinline__ void gemm_tile(bf16* As, bf16* Bs,
                                          const bf16* __restrict__ A,
                                          const bf16* __restrict__ W,
                                          bf16* __restrict__ Y,
                                          int N, int K, int m0, int n0) {
    const int tid  = threadIdx.x;
    const int lane = tid & 63;
    const int w    = tid >> 6;
    const int ml   = lane & 15;
    const int quad = lane >> 4;
    const int wm   = (w >> 1) * 64;
    const int wn   = (w & 1) * 64;
    const int sr   = lane >> 2;
    const int sc   = lane & 3;

    f32x4 acc[4][4] = {};

    for (int k0 = 0; k0 < K; k0 += 32) {
        __syncthreads();
#pragma unroll
        for (int ei = 0; ei < 2; ++ei) {
            const int e = w * 2 + ei;
            gld_lds16(A + (size_t)(m0 + e * 16 + sr) * K + k0 + sc * 8, &As[e * 512]);
            gld_lds16(W + (size_t)(n0 + e * 16 + sr) * K + k0 + sc * 8, &Bs[e * 512]);
        }
        __builtin_amdgcn_s_waitcnt(0);
        __syncthreads();

        bf16x8 af[4], bfr[4];
#pragma unroll
        for (int t = 0; t < 4; ++t) {
            af[t]  = *(const bf16x8*)&As[(wm + t * 16 + ml) * 32 + quad * 8];
            bfr[t] = *(const bf16x8*)&Bs[(wn + t * 16 + ml) * 32 + quad * 8];
        }
#pragma unroll
        for (int mt = 0; mt < 4; ++mt)
#pragma unroll
            for (int nt = 0; nt < 4; ++nt)
                acc[mt][nt] = MFMA16(af[mt], bfr[nt], acc[mt][nt]);
    }

#pragma unroll
    for (int mt = 0; mt < 4; ++mt)
#pragma unroll
        for (int nt = 0; nt < 4; ++nt)
#pragma unroll
            for (int r = 0; r < 4; ++r) {
                const int row = m0 + wm + mt * 16 + quad * 4 + r;
                const int col = n0 + wn + nt * 16 + ml;
                Y[(size_t)row * N + col] = (bf16)acc[mt][nt][r];
            }
}

// Fused projections: blocks 0..511 -> QK = x @ Wqk^T   [4096 x 2048]
//                    blocks 512..767 -> V^T = Wv @ x^T [1024 x 4096]
__global__ __launch_bounds__(256) void proj_fused(const bf16* __restrict__ xb,
                                                  const bf16* __restrict__ Wqk,
                                                  const bf16* __restrict__ Wvb,
                                                  bf16* __restrict__ QKb,
                                                  bf16* __restrict__ VtT) {
    __shared__ __align__(16) bf16 As[128 * 32];
    __shared__ __align__(16) bf16 Bs[128 * 32];
    const int bid = blockIdx.x;
    if (bid < 512) {
        gemm_tile(As, Bs, xb, Wqk, QKb, 2048, 1024, (bid >> 4) * 128, (bid & 15) * 128);
    } else {
        const int b2 = bid - 512;
        gemm_tile(As, Bs, Wvb, xb, VtT, 4096, 1024, (b2 >> 5) * 128, (b2 & 31) * 128);
    }
}

// ---------------------------------------------------------------------------
// Output GEMM: out[4096,1024] = Ab @ Wo^T, fp32 out. 64x128 tile -> 512 blocks.
// R5 single-buffer structure.
// ---------------------------------------------------------------------------
__global__ __launch_bounds__(256) void gemm_wo(const bf16* __restrict__ A,
                                               const bf16* __restrict__ W,
                                               float* __restrict__ Y) {
    __shared__ __align__(16) bf16 As[64 * 32];
    __shared__ __align__(16) bf16 Bs[128 * 32];
    const int tid  = threadIdx.x;
    const int lane = tid & 63;
    const int w    = tid >> 6;
    const int ml   = lane & 15;
    const int quad = lane >> 4;
    const int wm   = (w >> 1) * 32;
    const int wn   = (w & 1) * 64;
    const int m0   = blockIdx.y * 64;
    const int n0   = blockIdx.x * 128;
    const int sr   = lane >> 2;
    const int sc   = lane & 3;

    f32x4 acc[2][4] = {};

    for (int k0 = 0; k0 < 1024; k0 += 32) {
        __syncthreads();
        gld_lds16(A + (size_t)(m0 + w * 16 + sr) * 1024 + k0 + sc * 8, &As[w * 512]);
#pragma unroll
        for (int ei = 0; ei < 2; ++ei) {
            const int e = w * 2 + ei;
            gld_lds16(W + (size_t)(n0 + e * 16 + sr) * 1024 + k0 + sc * 8, &Bs[e * 512]);
        }
        __builtin_amdgcn_s_waitcnt(0);
        __syncthreads();

        bf16x8 af[2], bfr[4];
#pragma unroll
        for (int t = 0; t < 2; ++t)
            af[t] = *(const bf16x8*)&As[(wm + t * 16 + ml) * 32 + quad * 8];
#pragma unroll
        for (int t = 0; t < 4; ++t)
            bfr[t] = *(const bf16x8*)&Bs[(wn + t * 16 + ml) * 32 + quad * 8];
#pragma unroll
        for (int mt = 0; mt < 2; ++mt)
#pragma unroll
            for (int nt = 0; nt < 4; ++nt)
                acc[mt][nt] = MFMA16(af[mt], bfr[nt], acc[mt][nt]);
    }

#pragma unroll
    for (int mt = 0; mt < 2; ++mt)
#pragma unroll
        for (int nt = 0; nt < 4; ++nt)
#pragma unroll
            for (int r = 0; r < 4; ++r) {
                const int row = m0 + wm + mt * 16 + quad * 4 + r;
                const int col = n0 + wn + nt * 16 + ml;
                Y[(size_t)row * 1024 + col] = acc[mt][nt][r];
            }
}

// ---------------------------------------------------------------------------
// Flash attention v13: v12 structure (swapped QK^T, in-register P via
// cvt_pk+permlane32_swap, VALU L-sum, 32KB LDS, launch_bounds(256,4))
// + T5 s_setprio(1)/(0) around the MFMA clusters (m191: +4-7% on attn-shaped
// kernels with independent blocks and multiple blocks/CU).
// ---------------------------------------------------------------------------
__global__ __launch_bounds__(256, 4) void attn_mfma(const bf16* __restrict__ QKb,
                                                    const bf16* __restrict__ VtT,
                                                    bf16* __restrict__ Pbuf,
                                                    float* __restrict__ Lbuf) {
    const int bid = blockIdx.x;
    const int hb  = bid & 31;
    const int s   = 39 - (bid >> 5);      // slot, heavy (high tile) first
    int it, chunk;
    if (s < 4)       { it = s;                  chunk = 0; }
    else if (s < 12) { it = 4 + ((s - 4) >> 1); chunk = (s - 4) & 1; }
    else if (s < 24) { it = 8 + (s - 12) / 3;   chunk = (s - 12) % 3; }
    else             { it = 12 + ((s - 24) >> 2); chunk = (s - 24) & 3; }
    const int h = hb >> 1, b = hb & 1;

    const int tid  = threadIdx.x;
    const int lane = tid & 63;
    const int w    = tid >> 6;
    const int keyl = lane & 31;
    const int hi   = lane >> 5;

    __shared__ __align__(16) bf16 Ks[2][4096];
    __shared__ __align__(16) bf16 Vs[2][4096];

    const bf16* Qbase = QKb + (size_t)b * T_ * 2048 + (size_t)h * HD_;
    const bf16* Kbase = Qbase + 1024;
    const bf16* Vbase = VtT + (size_t)h * HD_ * 4096 + (size_t)b * T_;

    // Q rows for this wave; B-frag for swapped QK^T: col(q)=lane&31, k=8*hi+e
    const int qrow = it * 128 + w * 32 + keyl;
    bf16x8 qf[4];
#pragma unroll
    for (int dc = 0; dc < 4; ++dc)
        qf[dc] = *(const bf16x8*)(Qbase + (size_t)qrow * 2048 + dc * 16 + hi * 8);

    f32x16 o_acc[2] = {};
    float l_run = 0.f;

    const int ktbase  = chunk * 8;
    const int nrounds = min(8, 2 * it + 2 - ktbase);

    // Stage K[64 keys][64 d] and V^T[64 d][64 keys] as 128B rows with 16B
    // granules swizzled: granule g holds data-granule g ^ (row&7). Staged by
    // pre-swizzling the global source (LDS write is linear in lane order).
    auto stageKV = [&](int ktg, int buf) {
        const int k0 = ktg * 64;
#pragma unroll
        for (int ei = 0; ei < 2; ++ei) {
            const int e  = w * 2 + ei;              // 0..7 -> 8 rows per e
            const int rr = e * 8 + (lane >> 3);     // row (key for K, d for V)
            const int g  = (lane & 7) ^ (lane >> 3);// swizzled data granule
            gld_lds16(Kbase + (size_t)(k0 + rr) * 2048 + g * 8, &Ks[buf][e * 512]);
            gld_lds16(Vbase + (size_t)rr * 4096 + k0 + g * 8, &Vs[buf][e * 512]);
        }
    };

    auto round = [&](int cur, int ktg) {
        const int k0 = ktg * 64;
        const bool domask = (k0 + 63) > (it * 128 + w * 32);
        const int qg = it * 128 + w * 32 + keyl;
#pragma unroll
        for (int kh = 0; kh < 2; ++kh) {
            f32x16 sacc = {};
            __builtin_amdgcn_s_setprio(1);
#pragma unroll
            for (int dc = 0; dc < 4; ++dc) {
                // A-frag of K: row(key)=lane&31, k(d)=8*hi+e within chunk dc
                bf16x8 kf = *(const bf16x8*)&Ks[cur][(kh * 32 + keyl) * 64 +
                                                     (((dc << 1) | hi) ^ (keyl & 7)) * 8];
                sacc = MFMA32(kf, qf[dc], sacc);
            }
            __builtin_amdgcn_s_setprio(0);
#pragma unroll
            for (int c = 0; c < 2; ++c) {
                float p[8];
#pragma unroll
                for (int r8 = 0; r8 < 8; ++r8) {
                    float arg = sacc[8 * c + r8];
                    if (domask) {
                        const int kg = k0 + kh * 32 + 16 * c + 8 * (r8 >> 2) + 4 * hi + (r8 & 3);
                        if (kg > qg) arg = -1e30f;
                    }
                    p[r8] = __builtin_amdgcn_exp2f(arg);
                }
                l_run += ((p[0] + p[1]) + (p[2] + p[3])) + ((p[4] + p[5]) + (p[6] + p[7]));
                uint32_t a0, a1, b0, b1;
                asm("v_cvt_pk_bf16_f32 %0, %1, %2" : "=v"(a0) : "v"(p[0]), "v"(p[1]));
                asm("v_cvt_pk_bf16_f32 %0, %1, %2" : "=v"(a1) : "v"(p[2]), "v"(p[3]));
                asm("v_cvt_pk_bf16_f32 %0, %1, %2" : "=v"(b0) : "v"(p[4]), "v"(p[5]));
                asm("v_cvt_pk_bf16_f32 %0, %1, %2" : "=v"(b1) : "v"(p[6]), "v"(p[7]));
                asm("v_permlane32_swap_b32 %0, %1" : "+v"(a0), "+v"(b0));
                asm("v_permlane32_swap_b32 %0, %1" : "+v"(a1), "+v"(b1));
                union { uint32_t d[4]; bf16x8 v; } pa;
                pa.d[0] = a0; pa.d[1] = a1; pa.d[2] = b0; pa.d[3] = b1;
                const int kc = 2 * kh + c;
                __builtin_amdgcn_s_setprio(1);
#pragma unroll
                for (int dh = 0; dh < 2; ++dh) {
                    // B-frag of V: col(d)=lane&31, k(key)=8*hi+e within chunk kc
                    bf16x8 vf = *(const bf16x8*)&Vs[cur][(dh * 32 + keyl) * 64 +
                                                         (((kc << 1) | hi) ^ (keyl & 7)) * 8];
                    o_acc[dh] = MFMA32(pa.v, vf, o_acc[dh]);
                }
                __builtin_amdgcn_s_setprio(0);
            }
        }
    };

    stageKV(ktbase, 0);
    asm volatile("s_waitcnt vmcnt(0)" ::: "memory");
    asm volatile("s_barrier" ::: "memory");

    for (int j = 0; j < nrounds; ++j) {
        const int cur = j & 1;
        const int ktg = ktbase + j;
        if (j + 1 < nrounds) stageKV(ktg + 1, cur ^ 1);
        round(cur, ktg);
        if (j + 1 < nrounds) {
            asm volatile("s_waitcnt vmcnt(0)" ::: "memory");
            asm volatile("s_barrier" ::: "memory");
        }
    }

    const int slotIdx = hb * 40 + s;
    bf16* pb = Pbuf + (size_t)slotIdx * 8192;
#pragma unroll
    for (int dh = 0; dh < 2; ++dh)
#pragma unroll
        for (int r = 0; r < 16; ++r) {
            const int qloc = w * 32 + (r & 3) + 8 * (r >> 2) + 4 * hi;
            pb[qloc * 64 + dh * 32 + keyl] = (bf16)o_acc[dh][r];
        }
    const float l_tot = l_run + __shfl_xor(l_run, 32);
    if (hi == 0)
        Lbuf[slotIdx * 128 + w * 32 + keyl] = l_tot;
}

// ---------------------------------------------------------------------------
// Merge partials: grid 512 = (tile, h, b); sum <=4 chunks of 128x64,
// normalize, write Ab.
// ---------------------------------------------------------------------------
__global__ __launch_bounds__(256) void attn_merge(const bf16* __restrict__ Pbuf,
                                                  const float* __restrict__ Lbuf,
                                                  bf16* __restrict__ Ab) {
    const int gid = blockIdx.x;
    const int it  = gid >> 5;
    const int hb  = gid & 31;
    const int h = hb >> 1, b = hb & 1;
    int s0;
    if (it < 4)       s0 = it;
    else if (it < 8)  s0 = 4 + (it - 4) * 2;
    else if (it < 12) s0 = 12 + (it - 8) * 3;
    else              s0 = 24 + (it - 12) * 4;
    const int nch = (2 * it + 9) >> 3;

    const int tid = threadIdx.x;
    const int row = tid >> 1;            // 0..127
    const int cg  = (tid & 1) * 32;      // 0 or 32

    float acc[32] = {};
    float lsum = 0.f;
    for (int c = 0; c < nch; ++c) {
        const int slot = hb * 40 + s0 + c;
        lsum += Lbuf[slot * 128 + row];
        const bf16* pb = Pbuf + (size_t)slot * 8192 + row * 64 + cg;
#pragma unroll
        for (int g = 0; g < 4; ++g) {
            bf16x8 v = *(const bf16x8*)(pb + g * 8);
#pragma unroll
            for (int j = 0; j < 8; ++j) acc[g * 8 + j] += (float)v[j];
        }
    }
    const float rcl = 1.0f / lsum;
    bf16* dst = Ab + (size_t)(b * T_ + it * 128 + row) * 1024 + h * 64 + cg;
#pragma unroll
    for (int g = 0; g < 4; ++g) {
        bf16x8 o;
#pragma unroll
        for (int j = 0; j < 8; ++j) o[j] = (bf16)(acc[g * 8 + j] * rcl);
        *(bf16x8*)(dst + g * 8) = o;
    }
}

// ---------------------------------------------------------------------------
extern "C" void kernel_launch(void* const* d_in, const int* in_sizes, int n_in,
                              void* d_out, int out_size, void* d_ws, size_t ws_size,
                              hipStream_t stream) {
    const float* x  = (const float*)d_in[0];
    const float* Wq = (const float*)d_in[1];
    const float* Wk = (const float*)d_in[2];
    const float* Wv = (const float*)d_in[3];
    const float* Wo = (const float*)d_in[4];
    float* out = (float*)d_out;

    const size_t n_x = (size_t)B_ * T_ * C_;  // 4 Mi
    const size_t n_w = (size_t)C_ * C_;       // 1 Mi

    bf16* xb   = (bf16*)d_ws;        // 8 MB
    bf16* Wqk  = xb + n_x;           // 4 MB ([Wq; Wk])
    bf16* Wvb  = Wqk + 2 * n_w;      // 2 MB
    bf16* Wob  = Wvb + n_w;          // 2 MB
    bf16* QKb  = Wob + n_w;          // 16 MB (4096 x 2048)
    bf16* VtT  = QKb + 2 * n_x;      // 8 MB (1024 x 4096)
    bf16* Ab   = VtT + n_x;          // 8 MB (4096 x 1024)
    bf16* Pbuf = Ab + n_x;           // 21 MB (1280 x 128 x 64)
    float* Lbuf = (float*)(Pbuf + (size_t)1280 * 8192);  // 0.66 MB

    cast_all<<<5120, 256, 0, stream>>>(x, Wq, Wk, Wv, Wo, xb, Wqk, Wvb, Wob);

    proj_fused<<<768, 256, 0, stream>>>(xb, Wqk, Wvb, QKb, VtT);

    attn_mfma<<<1280, 256, 0, stream>>>(QKb, VtT, Pbuf, Lbuf);
    attn_merge<<<512, 256, 0, stream>>>(Pbuf, Lbuf, Ab);

    gemm_wo<<<dim3(1024 / 128, 4096 / 64), 256, 0, stream>>>(Ab, Wob, out);
}

// Round 9
// 171.867 us; speedup vs baseline: 1.2419x; 1.0221x over previous
//
#include <hip/hip_runtime.h>
#include <hip/hip_bf16.h>
#include <cstdint>
#include <cstddef>
#include <cmath>

#define B_  2
#define T_  2048
#define C_  1024
#define NH_ 16
#define HD_ 64

typedef __bf16 bf16;
typedef bf16  bf16x8 __attribute__((ext_vector_type(8)));
typedef bf16  bf16x4 __attribute__((ext_vector_type(4)));
typedef float f32x4  __attribute__((ext_vector_type(4)));
typedef float f32x16 __attribute__((ext_vector_type(16)));

#define MFMA16(a, b, c) __builtin_amdgcn_mfma_f32_16x16x32_bf16((a), (b), (c), 0, 0, 0)
#define MFMA32(a, b, c) __builtin_amdgcn_mfma_f32_32x32x16_bf16((a), (b), (c), 0, 0, 0)

// Async 16B global->LDS; LDS dest = wave-uniform base + lane*16.
__device__ __forceinline__ void gld_lds16(const bf16* g, bf16* lds_base_uniform) {
    __builtin_amdgcn_global_load_lds(
        (const __attribute__((address_space(1))) uint32_t*)g,
        (__attribute__((address_space(3))) uint32_t*)lds_base_uniform,
        16, 0, 0);
}

// ---------------------------------------------------------------------------
// Fused casts: blocks 0..4095 -> x (4 Mi elems); 4096..5119 -> all 4 weights.
// Wq is pre-scaled by 0.125*log2(e) so attention scores are exp2-ready.
// ---------------------------------------------------------------------------
__global__ __launch_bounds__(256) void cast_all(const float* __restrict__ x,
                                                const float* __restrict__ Wq,
                                                const float* __restrict__ Wk,
                                                const float* __restrict__ Wv,
                                                const float* __restrict__ Wo,
                                                bf16* __restrict__ xb,
                                                bf16* __restrict__ Wqk,
                                                bf16* __restrict__ Wvb,
                                                bf16* __restrict__ Wob) {
    const int bid = blockIdx.x;
    if (bid < 4096) {
        const int i = bid * 256 + threadIdx.x;
        float4 v = ((const float4*)x)[i];
        ((bf16x4*)xb)[i] = bf16x4{ (bf16)v.x, (bf16)v.y, (bf16)v.z, (bf16)v.w };
    } else {
        const float C1 = 0.1803368801111f;   // 0.125 * log2(e)
        const int i = (bid - 4096) * 256 + threadIdx.x;
        const int nw4 = C_ * C_ / 4;
        float4 q = ((const float4*)Wq)[i];
        float4 k = ((const float4*)Wk)[i];
        float4 v = ((const float4*)Wv)[i];
        float4 o = ((const float4*)Wo)[i];
        ((bf16x4*)Wqk)[i]       = bf16x4{ (bf16)(q.x * C1), (bf16)(q.y * C1),
                                          (bf16)(q.z * C1), (bf16)(q.w * C1) };
        ((bf16x4*)Wqk)[nw4 + i] = bf16x4{ (bf16)k.x, (bf16)k.y, (bf16)k.z, (bf16)k.w };
        ((bf16x4*)Wvb)[i]       = bf16x4{ (bf16)v.x, (bf16)v.y, (bf16)v.z, (bf16)v.w };
        ((bf16x4*)Wob)[i]       = bf16x4{ (bf16)o.x, (bf16)o.y, (bf16)o.z, (bf16)o.w };
    }
}

// ---------------------------------------------------------------------------
// 128x128 GEMM tile device fn (NT), R5 serial sync structure but BK=64:
// half the barrier/drain events, 2x compute per stall. 64-col LDS rows are
// stored with attn's proven 16B-granule XOR swizzle (granule g holds data
// granule g ^ (row&7)), realized by pre-swizzling the global source column
// (gld_lds writes linearly). Frag reads apply the same XOR -> 8 slots x 8
// lanes = wave64 b128 floor, no bank penalty.
// LDS: As 16KB + Bs 16KB = 32KB.
// ---------------------------------------------------------------------------
__device__ __forceinline__ void gemm_tile(bf16* As, bf16* Bs,
                                          const bf16* __restrict__ A,
                                          const bf16* __restrict__ W,
                                          bf16* __restrict__ Y,
                                          int N, int K, int m0, int n0) {
    const int tid  = threadIdx.x;
    const int lane = tid & 63;
    const int w    = tid >> 6;
    const int ml   = lane & 15;
    const int quad = lane >> 4;
    const int wm   = (w >> 1) * 64;
    const int wn   = (w & 1) * 64;
    const int srow = lane >> 3;              // 0..7 within an 8-row slice
    const int gsw  = (lane & 7) ^ srow;      // pre-swizzled source granule

    f32x4 acc[4][4] = {};

    for (int k0 = 0; k0 < K; k0 += 64) {
        __syncthreads();
#pragma unroll
        for (int ei = 0; ei < 4; ++ei) {
            const int e  = w * 4 + ei;       // 16 slices of 8 rows each
            const int rr = e * 8 + srow;
            gld_lds16(A + (size_t)(m0 + rr) * K + k0 + gsw * 8, &As[e * 512]);
            gld_lds16(W + (size_t)(n0 + rr) * K + k0 + gsw * 8, &Bs[e * 512]);
        }
        __builtin_amdgcn_s_waitcnt(0);
        __syncthreads();

#pragma unroll
        for (int kh = 0; kh < 2; ++kh) {
            bf16x8 af[4], bfr[4];
#pragma unroll
            for (int t = 0; t < 4; ++t) {
                const int sg = ((kh * 4 + quad) ^ (ml & 7)) * 8;
                af[t]  = *(const bf16x8*)&As[(wm + t * 16 + ml) * 64 + sg];
                bfr[t] = *(const bf16x8*)&Bs[(wn + t * 16 + ml) * 64 + sg];
            }
#pragma unroll
            for (int mt = 0; mt < 4; ++mt)
#pragma unroll
                for (int nt = 0; nt < 4; ++nt)
                    acc[mt][nt] = MFMA16(af[mt], bfr[nt], acc[mt][nt]);
        }
    }

#pragma unroll
    for (int mt = 0; mt < 4; ++mt)
#pragma unroll
        for (int nt = 0; nt < 4; ++nt)
#pragma unroll
            for (int r = 0; r < 4; ++r) {
                const int row = m0 + wm + mt * 16 + quad * 4 + r;
                const int col = n0 + wn + nt * 16 + ml;
                Y[(size_t)row * N + col] = (bf16)acc[mt][nt][r];
            }
}

// Fused projections: blocks 0..511 -> QK = x @ Wqk^T   [4096 x 2048]
//                    blocks 512..767 -> V^T = Wv @ x^T [1024 x 4096]
__global__ __launch_bounds__(256) void proj_fused(const bf16* __restrict__ xb,
                                                  const bf16* __restrict__ Wqk,
                                                  const bf16* __restrict__ Wvb,
                                                  bf16* __restrict__ QKb,
                                                  bf16* __restrict__ VtT) {
    __shared__ __align__(16) bf16 As[128 * 64];
    __shared__ __align__(16) bf16 Bs[128 * 64];
    const int bid = blockIdx.x;
    if (bid < 512) {
        gemm_tile(As, Bs, xb, Wqk, QKb, 2048, 1024, (bid >> 4) * 128, (bid & 15) * 128);
    } else {
        const int b2 = bid - 512;
        gemm_tile(As, Bs, Wvb, xb, VtT, 4096, 1024, (b2 >> 5) * 128, (b2 & 31) * 128);
    }
}

// ---------------------------------------------------------------------------
// Output GEMM: out[4096,1024] = Ab @ Wo^T, fp32 out. 64x128 tile -> 512 blocks.
// R5 serial sync structure, BK=64, same swizzled 64-col LDS layout.
// LDS = 8KB(A) + 16KB(B) = 24KB.
// ---------------------------------------------------------------------------
__global__ __launch_bounds__(256) void gemm_wo(const bf16* __restrict__ A,
                                               const bf16* __restrict__ W,
                                               float* __restrict__ Y) {
    __shared__ __align__(16) bf16 As[64 * 64];
    __shared__ __align__(16) bf16 Bs[128 * 64];
    const int tid  = threadIdx.x;
    const int lane = tid & 63;
    const int w    = tid >> 6;
    const int ml   = lane & 15;
    const int quad = lane >> 4;
    const int wm   = (w >> 1) * 32;
    const int wn   = (w & 1) * 64;
    const int m0   = blockIdx.y * 64;
    const int n0   = blockIdx.x * 128;
    const int srow = lane >> 3;
    const int gsw  = (lane & 7) ^ srow;

    f32x4 acc[2][4] = {};

    for (int k0 = 0; k0 < 1024; k0 += 64) {
        __syncthreads();
#pragma unroll
        for (int ei = 0; ei < 2; ++ei) {
            const int e  = w * 2 + ei;       // A: 8 slices
            const int rr = e * 8 + srow;
            gld_lds16(A + (size_t)(m0 + rr) * 1024 + k0 + gsw * 8, &As[e * 512]);
        }
#pragma unroll
        for (int ei = 0; ei < 4; ++ei) {
            const int e  = w * 4 + ei;       // B: 16 slices
            const int rr = e * 8 + srow;
            gld_lds16(W + (size_t)(n0 + rr) * 1024 + k0 + gsw * 8, &Bs[e * 512]);
        }
        __builtin_amdgcn_s_waitcnt(0);
        __syncthreads();

#pragma unroll
        for (int kh = 0; kh < 2; ++kh) {
            const int sg = ((kh * 4 + quad) ^ (ml & 7)) * 8;
            bf16x8 af[2], bfr[4];
#pragma unroll
            for (int t = 0; t < 2; ++t)
                af[t] = *(const bf16x8*)&As[(wm + t * 16 + ml) * 64 + sg];
#pragma unroll
            for (int t = 0; t < 4; ++t)
                bfr[t] = *(const bf16x8*)&Bs[(wn + t * 16 + ml) * 64 + sg];
#pragma unroll
            for (int mt = 0; mt < 2; ++mt)
#pragma unroll
                for (int nt = 0; nt < 4; ++nt)
                    acc[mt][nt] = MFMA16(af[mt], bfr[nt], acc[mt][nt]);
        }
    }

#pragma unroll
    for (int mt = 0; mt < 2; ++mt)
#pragma unroll
        for (int nt = 0; nt < 4; ++nt)
#pragma unroll
            for (int r = 0; r < 4; ++r) {
                const int row = m0 + wm + mt * 16 + quad * 4 + r;
                const int col = n0 + wn + nt * 16 + ml;
                Y[(size_t)row * 1024 + col] = acc[mt][nt][r];
            }
}

// ---------------------------------------------------------------------------
// Flash attention v13 (unchanged from R8): swapped QK^T, in-register P via
// cvt_pk+permlane32_swap (T12), VALU L-sum, 32KB LDS, launch_bounds(256,4),
// T5 setprio around MFMA clusters.
// ---------------------------------------------------------------------------
__global__ __launch_bounds__(256, 4) void attn_mfma(const bf16* __restrict__ QKb,
                                                    const bf16* __restrict__ VtT,
                                                    bf16* __restrict__ Pbuf,
                                                    float* __restrict__ Lbuf) {
    const int bid = blockIdx.x;
    const int hb  = bid & 31;
    const int s   = 39 - (bid >> 5);      // slot, heavy (high tile) first
    int it, chunk;
    if (s < 4)       { it = s;                  chunk = 0; }
    else if (s < 12) { it = 4 + ((s - 4) >> 1); chunk = (s - 4) & 1; }
    else if (s < 24) { it = 8 + (s - 12) / 3;   chunk = (s - 12) % 3; }
    else             { it = 12 + ((s - 24) >> 2); chunk = (s - 24) & 3; }
    const int h = hb >> 1, b = hb & 1;

    const int tid  = threadIdx.x;
    const int lane = tid & 63;
    const int w    = tid >> 6;
    const int keyl = lane & 31;
    const int hi   = lane >> 5;

    __shared__ __align__(16) bf16 Ks[2][4096];
    __shared__ __align__(16) bf16 Vs[2][4096];

    const bf16* Qbase = QKb + (size_t)b * T_ * 2048 + (size_t)h * HD_;
    const bf16* Kbase = Qbase + 1024;
    const bf16* Vbase = VtT + (size_t)h * HD_ * 4096 + (size_t)b * T_;

    // Q rows for this wave; B-frag for swapped QK^T: col(q)=lane&31, k=8*hi+e
    const int qrow = it * 128 + w * 32 + keyl;
    bf16x8 qf[4];
#pragma unroll
    for (int dc = 0; dc < 4; ++dc)
        qf[dc] = *(const bf16x8*)(Qbase + (size_t)qrow * 2048 + dc * 16 + hi * 8);

    f32x16 o_acc[2] = {};
    float l_run = 0.f;

    const int ktbase  = chunk * 8;
    const int nrounds = min(8, 2 * it + 2 - ktbase);

    auto stageKV = [&](int ktg, int buf) {
        const int k0 = ktg * 64;
#pragma unroll
        for (int ei = 0; ei < 2; ++ei) {
            const int e  = w * 2 + ei;              // 0..7 -> 8 rows per e
            const int rr = e * 8 + (lane >> 3);     // row (key for K, d for V)
            const int g  = (lane & 7) ^ (lane >> 3);// swizzled data granule
            gld_lds16(Kbase + (size_t)(k0 + rr) * 2048 + g * 8, &Ks[buf][e * 512]);
            gld_lds16(Vbase + (size_t)rr * 4096 + k0 + g * 8, &Vs[buf][e * 512]);
        }
    };

    auto round = [&](int cur, int ktg) {
        const int k0 = ktg * 64;
        const bool domask = (k0 + 63) > (it * 128 + w * 32);
        const int qg = it * 128 + w * 32 + keyl;
#pragma unroll
        for (int kh = 0; kh < 2; ++kh) {
            f32x16 sacc = {};
            __builtin_amdgcn_s_setprio(1);
#pragma unroll
            for (int dc = 0; dc < 4; ++dc) {
                bf16x8 kf = *(const bf16x8*)&Ks[cur][(kh * 32 + keyl) * 64 +
                                                     (((dc << 1) | hi) ^ (keyl & 7)) * 8];
                sacc = MFMA32(kf, qf[dc], sacc);
            }
            __builtin_amdgcn_s_setprio(0);
#pragma unroll
            for (int c = 0; c < 2; ++c) {
                float p[8];
#pragma unroll
                for (int r8 = 0; r8 < 8; ++r8) {
                    float arg = sacc[8 * c + r8];
                    if (domask) {
                        const int kg = k0 + kh * 32 + 16 * c + 8 * (r8 >> 2) + 4 * hi + (r8 & 3);
                        if (kg > qg) arg = -1e30f;
                    }
                    p[r8] = __builtin_amdgcn_exp2f(arg);
                }
                l_run += ((p[0] + p[1]) + (p[2] + p[3])) + ((p[4] + p[5]) + (p[6] + p[7]));
                uint32_t a0, a1, b0, b1;
                asm("v_cvt_pk_bf16_f32 %0, %1, %2" : "=v"(a0) : "v"(p[0]), "v"(p[1]));
                asm("v_cvt_pk_bf16_f32 %0, %1, %2" : "=v"(a1) : "v"(p[2]), "v"(p[3]));
                asm("v_cvt_pk_bf16_f32 %0, %1, %2" : "=v"(b0) : "v"(p[4]), "v"(p[5]));
                asm("v_cvt_pk_bf16_f32 %0, %1, %2" : "=v"(b1) : "v"(p[6]), "v"(p[7]));
                asm("v_permlane32_swap_b32 %0, %1" : "+v"(a0), "+v"(b0));
                asm("v_permlane32_swap_b32 %0, %1" : "+v"(a1), "+v"(b1));
                union { uint32_t d[4]; bf16x8 v; } pa;
                pa.d[0] = a0; pa.d[1] = a1; pa.d[2] = b0; pa.d[3] = b1;
                const int kc = 2 * kh + c;
                __builtin_amdgcn_s_setprio(1);
#pragma unroll
                for (int dh = 0; dh < 2; ++dh) {
                    bf16x8 vf = *(const bf16x8*)&Vs[cur][(dh * 32 + keyl) * 64 +
                                                         (((kc << 1) | hi) ^ (keyl & 7)) * 8];
                    o_acc[dh] = MFMA32(pa.v, vf, o_acc[dh]);
                }
                __builtin_amdgcn_s_setprio(0);
            }
        }
    };

    stageKV(ktbase, 0);
    asm volatile("s_waitcnt vmcnt(0)" ::: "memory");
    asm volatile("s_barrier" ::: "memory");

    for (int j = 0; j < nrounds; ++j) {
        const int cur = j & 1;
        const int ktg = ktbase + j;
        if (j + 1 < nrounds) stageKV(ktg + 1, cur ^ 1);
        round(cur, ktg);
        if (j + 1 < nrounds) {
            asm volatile("s_waitcnt vmcnt(0)" ::: "memory");
            asm volatile("s_barrier" ::: "memory");
        }
    }

    const int slotIdx = hb * 40 + s;
    bf16* pb = Pbuf + (size_t)slotIdx * 8192;
#pragma unroll
    for (int dh = 0; dh < 2; ++dh)
#pragma unroll
        for (int r = 0; r < 16; ++r) {
            const int qloc = w * 32 + (r & 3) + 8 * (r >> 2) + 4 * hi;
            pb[qloc * 64 + dh * 32 + keyl] = (bf16)o_acc[dh][r];
        }
    const float l_tot = l_run + __shfl_xor(l_run, 32);
    if (hi == 0)
        Lbuf[slotIdx * 128 + w * 32 + keyl] = l_tot;
}

// ---------------------------------------------------------------------------
// Merge partials: grid 512 = (tile, h, b); sum <=4 chunks of 128x64,
// normalize, write Ab.
// ---------------------------------------------------------------------------
__global__ __launch_bounds__(256) void attn_merge(const bf16* __restrict__ Pbuf,
                                                  const float* __restrict__ Lbuf,
                                                  bf16* __restrict__ Ab) {
    const int gid = blockIdx.x;
    const int it  = gid >> 5;
    const int hb  = gid & 31;
    const int h = hb >> 1, b = hb & 1;
    int s0;
    if (it < 4)       s0 = it;
    else if (it < 8)  s0 = 4 + (it - 4) * 2;
    else if (it < 12) s0 = 12 + (it - 8) * 3;
    else              s0 = 24 + (it - 12) * 4;
    const int nch = (2 * it + 9) >> 3;

    const int tid = threadIdx.x;
    const int row = tid >> 1;            // 0..127
    const int cg  = (tid & 1) * 32;      // 0 or 32

    float acc[32] = {};
    float lsum = 0.f;
    for (int c = 0; c < nch; ++c) {
        const int slot = hb * 40 + s0 + c;
        lsum += Lbuf[slot * 128 + row];
        const bf16* pb = Pbuf + (size_t)slot * 8192 + row * 64 + cg;
#pragma unroll
        for (int g = 0; g < 4; ++g) {
            bf16x8 v = *(const bf16x8*)(pb + g * 8);
#pragma unroll
            for (int j = 0; j < 8; ++j) acc[g * 8 + j] += (float)v[j];
        }
    }
    const float rcl = 1.0f / lsum;
    bf16* dst = Ab + (size_t)(b * T_ + it * 128 + row) * 1024 + h * 64 + cg;
#pragma unroll
    for (int g = 0; g < 4; ++g) {
        bf16x8 o;
#pragma unroll
        for (int j = 0; j < 8; ++j) o[j] = (bf16)(acc[g * 8 + j] * rcl);
        *(bf16x8*)(dst + g * 8) = o;
    }
}

// ---------------------------------------------------------------------------
extern "C" void kernel_launch(void* const* d_in, const int* in_sizes, int n_in,
                              void* d_out, int out_size, void* d_ws, size_t ws_size,
                              hipStream_t stream) {
    const float* x  = (const float*)d_in[0];
    const float* Wq = (const float*)d_in[1];
    const float* Wk = (const float*)d_in[2];
    const float* Wv = (const float*)d_in[3];
    const float* Wo = (const float*)d_in[4];
    float* out = (float*)d_out;

    const size_t n_x = (size_t)B_ * T_ * C_;  // 4 Mi
    const size_t n_w = (size_t)C_ * C_;       // 1 Mi

    bf16* xb   = (bf16*)d_ws;        // 8 MB
    bf16* Wqk  = xb + n_x;           // 4 MB ([Wq; Wk])
    bf16* Wvb  = Wqk + 2 * n_w;      // 2 MB
    bf16* Wob  = Wvb + n_w;          // 2 MB
    bf16* QKb  = Wob + n_w;          // 16 MB (4096 x 2048)
    bf16* VtT  = QKb + 2 * n_x;      // 8 MB (1024 x 4096)
    bf16* Ab   = VtT + n_x;          // 8 MB (4096 x 1024)
    bf16* Pbuf = Ab + n_x;           // 21 MB (1280 x 128 x 64)
    float* Lbuf = (float*)(Pbuf + (size_t)1280 * 8192);  // 0.66 MB

    cast_all<<<5120, 256, 0, stream>>>(x, Wq, Wk, Wv, Wo, xb, Wqk, Wvb, Wob);

    proj_fused<<<768, 256, 0, stream>>>(xb, Wqk, Wvb, QKb, VtT);

    attn_mfma<<<1280, 256, 0, stream>>>(QKb, VtT, Pbuf, Lbuf);
    attn_merge<<<512, 256, 0, stream>>>(Pbuf, Lbuf, Ab);

    gemm_wo<<<dim3(1024 / 128, 4096 / 64), 256, 0, stream>>>(Ab, Wob, out);
}

// Round 10
// 168.395 us; speedup vs baseline: 1.2675x; 1.0206x over previous
//
#include <hip/hip_runtime.h>
#include <hip/hip_bf16.h>
#include <cstdint>
#include <cstddef>
#include <cmath>

#define B_  2
#define T_  2048
#define C_  1024
#define NH_ 16
#define HD_ 64

typedef __bf16 bf16;
typedef bf16  bf16x8 __attribute__((ext_vector_type(8)));
typedef bf16  bf16x4 __attribute__((ext_vector_type(4)));
typedef float f32x4  __attribute__((ext_vector_type(4)));
typedef float f32x16 __attribute__((ext_vector_type(16)));

#define MFMA16(a, b, c) __builtin_amdgcn_mfma_f32_16x16x32_bf16((a), (b), (c), 0, 0, 0)
#define MFMA32(a, b, c) __builtin_amdgcn_mfma_f32_32x32x16_bf16((a), (b), (c), 0, 0, 0)

// Async 16B global->LDS; LDS dest = wave-uniform base + lane*16.
__device__ __forceinline__ void gld_lds16(const bf16* g, bf16* lds_base_uniform) {
    __builtin_amdgcn_global_load_lds(
        (const __attribute__((address_space(1))) uint32_t*)g,
        (__attribute__((address_space(3))) uint32_t*)lds_base_uniform,
        16, 0, 0);
}

// ---------------------------------------------------------------------------
// Fused casts: blocks 0..4095 -> x (4 Mi elems); 4096..5119 -> all 4 weights.
// Wq is pre-scaled by 0.125*log2(e) so attention scores are exp2-ready.
// ---------------------------------------------------------------------------
__global__ __launch_bounds__(256) void cast_all(const float* __restrict__ x,
                                                const float* __restrict__ Wq,
                                                const float* __restrict__ Wk,
                                                const float* __restrict__ Wv,
                                                const float* __restrict__ Wo,
                                                bf16* __restrict__ xb,
                                                bf16* __restrict__ Wqk,
                                                bf16* __restrict__ Wvb,
                                                bf16* __restrict__ Wob) {
    const int bid = blockIdx.x;
    if (bid < 4096) {
        const int i = bid * 256 + threadIdx.x;
        float4 v = ((const float4*)x)[i];
        ((bf16x4*)xb)[i] = bf16x4{ (bf16)v.x, (bf16)v.y, (bf16)v.z, (bf16)v.w };
    } else {
        const float C1 = 0.1803368801111f;   // 0.125 * log2(e)
        const int i = (bid - 4096) * 256 + threadIdx.x;
        const int nw4 = C_ * C_ / 4;
        float4 q = ((const float4*)Wq)[i];
        float4 k = ((const float4*)Wk)[i];
        float4 v = ((const float4*)Wv)[i];
        float4 o = ((const float4*)Wo)[i];
        ((bf16x4*)Wqk)[i]       = bf16x4{ (bf16)(q.x * C1), (bf16)(q.y * C1),
                                          (bf16)(q.z * C1), (bf16)(q.w * C1) };
        ((bf16x4*)Wqk)[nw4 + i] = bf16x4{ (bf16)k.x, (bf16)k.y, (bf16)k.z, (bf16)k.w };
        ((bf16x4*)Wvb)[i]       = bf16x4{ (bf16)v.x, (bf16)v.y, (bf16)v.z, (bf16)v.w };
        ((bf16x4*)Wob)[i]       = bf16x4{ (bf16)o.x, (bf16)o.y, (bf16)o.z, (bf16)o.w };
    }
}

// ---------------------------------------------------------------------------
// 128x128 GEMM tile device fn (NT), R9 structure: serial sync, BK=64,
// XOR-swizzled 64-col LDS rows (granule g holds data granule g ^ (row&7)).
// ---------------------------------------------------------------------------
__device__ __forceinline__ void gemm_tile(bf16* As, bf16* Bs,
                                          const bf16* __restrict__ A,
                                          const bf16* __restrict__ W,
                                          bf16* __restrict__ Y,
                                          int N, int K, int m0, int n0) {
    const int tid  = threadIdx.x;
    const int lane = tid & 63;
    const int w    = tid >> 6;
    const int ml   = lane & 15;
    const int quad = lane >> 4;
    const int wm   = (w >> 1) * 64;
    const int wn   = (w & 1) * 64;
    const int srow = lane >> 3;              // 0..7 within an 8-row slice
    const int gsw  = (lane & 7) ^ srow;      // pre-swizzled source granule

    f32x4 acc[4][4] = {};

    for (int k0 = 0; k0 < K; k0 += 64) {
        __syncthreads();
#pragma unroll
        for (int ei = 0; ei < 4; ++ei) {
            const int e  = w * 4 + ei;       // 16 slices of 8 rows each
            const int rr = e * 8 + srow;
            gld_lds16(A + (size_t)(m0 + rr) * K + k0 + gsw * 8, &As[e * 512]);
            gld_lds16(W + (size_t)(n0 + rr) * K + k0 + gsw * 8, &Bs[e * 512]);
        }
        __builtin_amdgcn_s_waitcnt(0);
        __syncthreads();

#pragma unroll
        for (int kh = 0; kh < 2; ++kh) {
            bf16x8 af[4], bfr[4];
#pragma unroll
            for (int t = 0; t < 4; ++t) {
                const int sg = ((kh * 4 + quad) ^ (ml & 7)) * 8;
                af[t]  = *(const bf16x8*)&As[(wm + t * 16 + ml) * 64 + sg];
                bfr[t] = *(const bf16x8*)&Bs[(wn + t * 16 + ml) * 64 + sg];
            }
#pragma unroll
            for (int mt = 0; mt < 4; ++mt)
#pragma unroll
                for (int nt = 0; nt < 4; ++nt)
                    acc[mt][nt] = MFMA16(af[mt], bfr[nt], acc[mt][nt]);
        }
    }

#pragma unroll
    for (int mt = 0; mt < 4; ++mt)
#pragma unroll
        for (int nt = 0; nt < 4; ++nt)
#pragma unroll
            for (int r = 0; r < 4; ++r) {
                const int row = m0 + wm + mt * 16 + quad * 4 + r;
                const int col = n0 + wn + nt * 16 + ml;
                Y[(size_t)row * N + col] = (bf16)acc[mt][nt][r];
            }
}

// Fused projections: swz 0..511 -> QK = x @ Wqk^T   [4096 x 2048]
//                    swz 512..767 -> V^T = Wv @ x^T [1024 x 4096]
// T1 XCD swizzle: grid 768 = 8 XCDs x 96 contiguous tiles; consecutive
// swz share A-panels -> per-XCD L2 reuse (bijective: 768 % 8 == 0).
__global__ __launch_bounds__(256) void proj_fused(const bf16* __restrict__ xb,
                                                  const bf16* __restrict__ Wqk,
                                                  const bf16* __restrict__ Wvb,
                                                  bf16* __restrict__ QKb,
                                                  bf16* __restrict__ VtT) {
    __shared__ __align__(16) bf16 As[128 * 64];
    __shared__ __align__(16) bf16 Bs[128 * 64];
    const int bid0 = blockIdx.x;
    const int bid  = (bid0 & 7) * 96 + (bid0 >> 3);
    if (bid < 512) {
        gemm_tile(As, Bs, xb, Wqk, QKb, 2048, 1024, (bid >> 4) * 128, (bid & 15) * 128);
    } else {
        const int b2 = bid - 512;
        gemm_tile(As, Bs, Wvb, xb, VtT, 4096, 1024, (b2 >> 5) * 128, (b2 & 31) * 128);
    }
}

// ---------------------------------------------------------------------------
// Output GEMM: out[4096,1024] = Ab @ Wo^T, fp32 out. 64x128 tile, 1D grid of
// 512 with T1 XCD swizzle (512 = 8 x 64): each XCD gets 8 m-panels (1 MB Ab)
// + full Wo (2 MB) = 3 MB, L2-resident. R9 serial BK=64 swizzled-LDS.
// ---------------------------------------------------------------------------
__global__ __launch_bounds__(256) void gemm_wo(const bf16* __restrict__ A,
                                               const bf16* __restrict__ W,
                                               float* __restrict__ Y) {
    __shared__ __align__(16) bf16 As[64 * 64];
    __shared__ __align__(16) bf16 Bs[128 * 64];
    const int tid  = threadIdx.x;
    const int lane = tid & 63;
    const int w    = tid >> 6;
    const int ml   = lane & 15;
    const int quad = lane >> 4;
    const int wm   = (w >> 1) * 32;
    const int wn   = (w & 1) * 64;
    const int bid0 = blockIdx.x;
    const int swz  = (bid0 & 7) * 64 + (bid0 >> 3);
    const int m0   = (swz >> 3) * 64;
    const int n0   = (swz & 7) * 128;
    const int srow = lane >> 3;
    const int gsw  = (lane & 7) ^ srow;

    f32x4 acc[2][4] = {};

    for (int k0 = 0; k0 < 1024; k0 += 64) {
        __syncthreads();
#pragma unroll
        for (int ei = 0; ei < 2; ++ei) {
            const int e  = w * 2 + ei;       // A: 8 slices
            const int rr = e * 8 + srow;
            gld_lds16(A + (size_t)(m0 + rr) * 1024 + k0 + gsw * 8, &As[e * 512]);
        }
#pragma unroll
        for (int ei = 0; ei < 4; ++ei) {
            const int e  = w * 4 + ei;       // B: 16 slices
            const int rr = e * 8 + srow;
            gld_lds16(W + (size_t)(n0 + rr) * 1024 + k0 + gsw * 8, &Bs[e * 512]);
        }
        __builtin_amdgcn_s_waitcnt(0);
        __syncthreads();

#pragma unroll
        for (int kh = 0; kh < 2; ++kh) {
            const int sg = ((kh * 4 + quad) ^ (ml & 7)) * 8;
            bf16x8 af[2], bfr[4];
#pragma unroll
            for (int t = 0; t < 2; ++t)
                af[t] = *(const bf16x8*)&As[(wm + t * 16 + ml) * 64 + sg];
#pragma unroll
            for (int t = 0; t < 4; ++t)
                bfr[t] = *(const bf16x8*)&Bs[(wn + t * 16 + ml) * 64 + sg];
#pragma unroll
            for (int mt = 0; mt < 2; ++mt)
#pragma unroll
                for (int nt = 0; nt < 4; ++nt)
                    acc[mt][nt] = MFMA16(af[mt], bfr[nt], acc[mt][nt]);
        }
    }

#pragma unroll
    for (int mt = 0; mt < 2; ++mt)
#pragma unroll
        for (int nt = 0; nt < 4; ++nt)
#pragma unroll
            for (int r = 0; r < 4; ++r) {
                const int row = m0 + wm + mt * 16 + quad * 4 + r;
                const int col = n0 + wn + nt * 16 + ml;
                Y[(size_t)row * 1024 + col] = acc[mt][nt][r];
            }
}

// ---------------------------------------------------------------------------
// Flash attention v13 (unchanged from R8/R9): swapped QK^T, in-register P via
// cvt_pk+permlane32_swap (T12), VALU L-sum, 32KB LDS, launch_bounds(256,4),
// T5 setprio around MFMA clusters.
// ---------------------------------------------------------------------------
__global__ __launch_bounds__(256, 4) void attn_mfma(const bf16* __restrict__ QKb,
                                                    const bf16* __restrict__ VtT,
                                                    bf16* __restrict__ Pbuf,
                                                    float* __restrict__ Lbuf) {
    const int bid = blockIdx.x;
    const int hb  = bid & 31;
    const int s   = 39 - (bid >> 5);      // slot, heavy (high tile) first
    int it, chunk;
    if (s < 4)       { it = s;                  chunk = 0; }
    else if (s < 12) { it = 4 + ((s - 4) >> 1); chunk = (s - 4) & 1; }
    else if (s < 24) { it = 8 + (s - 12) / 3;   chunk = (s - 12) % 3; }
    else             { it = 12 + ((s - 24) >> 2); chunk = (s - 24) & 3; }
    const int h = hb >> 1, b = hb & 1;

    const int tid  = threadIdx.x;
    const int lane = tid & 63;
    const int w    = tid >> 6;
    const int keyl = lane & 31;
    const int hi   = lane >> 5;

    __shared__ __align__(16) bf16 Ks[2][4096];
    __shared__ __align__(16) bf16 Vs[2][4096];

    const bf16* Qbase = QKb + (size_t)b * T_ * 2048 + (size_t)h * HD_;
    const bf16* Kbase = Qbase + 1024;
    const bf16* Vbase = VtT + (size_t)h * HD_ * 4096 + (size_t)b * T_;

    // Q rows for this wave; B-frag for swapped QK^T: col(q)=lane&31, k=8*hi+e
    const int qrow = it * 128 + w * 32 + keyl;
    bf16x8 qf[4];
#pragma unroll
    for (int dc = 0; dc < 4; ++dc)
        qf[dc] = *(const bf16x8*)(Qbase + (size_t)qrow * 2048 + dc * 16 + hi * 8);

    f32x16 o_acc[2] = {};
    float l_run = 0.f;

    const int ktbase  = chunk * 8;
    const int nrounds = min(8, 2 * it + 2 - ktbase);

    auto stageKV = [&](int ktg, int buf) {
        const int k0 = ktg * 64;
#pragma unroll
        for (int ei = 0; ei < 2; ++ei) {
            const int e  = w * 2 + ei;              // 0..7 -> 8 rows per e
            const int rr = e * 8 + (lane >> 3);     // row (key for K, d for V)
            const int g  = (lane & 7) ^ (lane >> 3);// swizzled data granule
            gld_lds16(Kbase + (size_t)(k0 + rr) * 2048 + g * 8, &Ks[buf][e * 512]);
            gld_lds16(Vbase + (size_t)rr * 4096 + k0 + g * 8, &Vs[buf][e * 512]);
        }
    };

    auto round = [&](int cur, int ktg) {
        const int k0 = ktg * 64;
        const bool domask = (k0 + 63) > (it * 128 + w * 32);
        const int qg = it * 128 + w * 32 + keyl;
#pragma unroll
        for (int kh = 0; kh < 2; ++kh) {
            f32x16 sacc = {};
            __builtin_amdgcn_s_setprio(1);
#pragma unroll
            for (int dc = 0; dc < 4; ++dc) {
                bf16x8 kf = *(const bf16x8*)&Ks[cur][(kh * 32 + keyl) * 64 +
                                                     (((dc << 1) | hi) ^ (keyl & 7)) * 8];
                sacc = MFMA32(kf, qf[dc], sacc);
            }
            __builtin_amdgcn_s_setprio(0);
#pragma unroll
            for (int c = 0; c < 2; ++c) {
                float p[8];
#pragma unroll
                for (int r8 = 0; r8 < 8; ++r8) {
                    float arg = sacc[8 * c + r8];
                    if (domask) {
                        const int kg = k0 + kh * 32 + 16 * c + 8 * (r8 >> 2) + 4 * hi + (r8 & 3);
                        if (kg > qg) arg = -1e30f;
                    }
                    p[r8] = __builtin_amdgcn_exp2f(arg);
                }
                l_run += ((p[0] + p[1]) + (p[2] + p[3])) + ((p[4] + p[5]) + (p[6] + p[7]));
                uint32_t a0, a1, b0, b1;
                asm("v_cvt_pk_bf16_f32 %0, %1, %2" : "=v"(a0) : "v"(p[0]), "v"(p[1]));
                asm("v_cvt_pk_bf16_f32 %0, %1, %2" : "=v"(a1) : "v"(p[2]), "v"(p[3]));
                asm("v_cvt_pk_bf16_f32 %0, %1, %2" : "=v"(b0) : "v"(p[4]), "v"(p[5]));
                asm("v_cvt_pk_bf16_f32 %0, %1, %2" : "=v"(b1) : "v"(p[6]), "v"(p[7]));
                asm("v_permlane32_swap_b32 %0, %1" : "+v"(a0), "+v"(b0));
                asm("v_permlane32_swap_b32 %0, %1" : "+v"(a1), "+v"(b1));
                union { uint32_t d[4]; bf16x8 v; } pa;
                pa.d[0] = a0; pa.d[1] = a1; pa.d[2] = b0; pa.d[3] = b1;
                const int kc = 2 * kh + c;
                __builtin_amdgcn_s_setprio(1);
#pragma unroll
                for (int dh = 0; dh < 2; ++dh) {
                    bf16x8 vf = *(const bf16x8*)&Vs[cur][(dh * 32 + keyl) * 64 +
                                                         (((kc << 1) | hi) ^ (keyl & 7)) * 8];
                    o_acc[dh] = MFMA32(pa.v, vf, o_acc[dh]);
                }
                __builtin_amdgcn_s_setprio(0);
            }
        }
    };

    stageKV(ktbase, 0);
    asm volatile("s_waitcnt vmcnt(0)" ::: "memory");
    asm volatile("s_barrier" ::: "memory");

    for (int j = 0; j < nrounds; ++j) {
        const int cur = j & 1;
        const int ktg = ktbase + j;
        if (j + 1 < nrounds) stageKV(ktg + 1, cur ^ 1);
        round(cur, ktg);
        if (j + 1 < nrounds) {
            asm volatile("s_waitcnt vmcnt(0)" ::: "memory");
            asm volatile("s_barrier" ::: "memory");
        }
    }

    const int slotIdx = hb * 40 + s;
    bf16* pb = Pbuf + (size_t)slotIdx * 8192;
#pragma unroll
    for (int dh = 0; dh < 2; ++dh)
#pragma unroll
        for (int r = 0; r < 16; ++r) {
            const int qloc = w * 32 + (r & 3) + 8 * (r >> 2) + 4 * hi;
            pb[qloc * 64 + dh * 32 + keyl] = (bf16)o_acc[dh][r];
        }
    const float l_tot = l_run + __shfl_xor(l_run, 32);
    if (hi == 0)
        Lbuf[slotIdx * 128 + w * 32 + keyl] = l_tot;
}

// ---------------------------------------------------------------------------
// Merge partials: grid 512 = (tile, h, b); sum <=4 chunks of 128x64,
// normalize, write Ab.
// ---------------------------------------------------------------------------
__global__ __launch_bounds__(256) void attn_merge(const bf16* __restrict__ Pbuf,
                                                  const float* __restrict__ Lbuf,
                                                  bf16* __restrict__ Ab) {
    const int gid = blockIdx.x;
    const int it  = gid >> 5;
    const int hb  = gid & 31;
    const int h = hb >> 1, b = hb & 1;
    int s0;
    if (it < 4)       s0 = it;
    else if (it < 8)  s0 = 4 + (it - 4) * 2;
    else if (it < 12) s0 = 12 + (it - 8) * 3;
    else              s0 = 24 + (it - 12) * 4;
    const int nch = (2 * it + 9) >> 3;

    const int tid = threadIdx.x;
    const int row = tid >> 1;            // 0..127
    const int cg  = (tid & 1) * 32;      // 0 or 32

    float acc[32] = {};
    float lsum = 0.f;
    for (int c = 0; c < nch; ++c) {
        const int slot = hb * 40 + s0 + c;
        lsum += Lbuf[slot * 128 + row];
        const bf16* pb = Pbuf + (size_t)slot * 8192 + row * 64 + cg;
#pragma unroll
        for (int g = 0; g < 4; ++g) {
            bf16x8 v = *(const bf16x8*)(pb + g * 8);
#pragma unroll
            for (int j = 0; j < 8; ++j) acc[g * 8 + j] += (float)v[j];
        }
    }
    const float rcl = 1.0f / lsum;
    bf16* dst = Ab + (size_t)(b * T_ + it * 128 + row) * 1024 + h * 64 + cg;
#pragma unroll
    for (int g = 0; g < 4; ++g) {
        bf16x8 o;
#pragma unroll
        for (int j = 0; j < 8; ++j) o[j] = (bf16)(acc[g * 8 + j] * rcl);
        *(bf16x8*)(dst + g * 8) = o;
    }
}

// ---------------------------------------------------------------------------
extern "C" void kernel_launch(void* const* d_in, const int* in_sizes, int n_in,
                              void* d_out, int out_size, void* d_ws, size_t ws_size,
                              hipStream_t stream) {
    const float* x  = (const float*)d_in[0];
    const float* Wq = (const float*)d_in[1];
    const float* Wk = (const float*)d_in[2];
    const float* Wv = (const float*)d_in[3];
    const float* Wo = (const float*)d_in[4];
    float* out = (float*)d_out;

    const size_t n_x = (size_t)B_ * T_ * C_;  // 4 Mi
    const size_t n_w = (size_t)C_ * C_;       // 1 Mi

    bf16* xb   = (bf16*)d_ws;        // 8 MB
    bf16* Wqk  = xb + n_x;           // 4 MB ([Wq; Wk])
    bf16* Wvb  = Wqk + 2 * n_w;      // 2 MB
    bf16* Wob  = Wvb + n_w;          // 2 MB
    bf16* QKb  = Wob + n_w;          // 16 MB (4096 x 2048)
    bf16* VtT  = QKb + 2 * n_x;      // 8 MB (1024 x 4096)
    bf16* Ab   = VtT + n_x;          // 8 MB (4096 x 1024)
    bf16* Pbuf = Ab + n_x;           // 21 MB (1280 x 128 x 64)
    float* Lbuf = (float*)(Pbuf + (size_t)1280 * 8192);  // 0.66 MB

    cast_all<<<5120, 256, 0, stream>>>(x, Wq, Wk, Wv, Wo, xb, Wqk, Wvb, Wob);

    proj_fused<<<768, 256, 0, stream>>>(xb, Wqk, Wvb, QKb, VtT);

    attn_mfma<<<1280, 256, 0, stream>>>(QKb, VtT, Pbuf, Lbuf);
    attn_merge<<<512, 256, 0, stream>>>(Pbuf, Lbuf, Ab);

    gemm_wo<<<512, 256, 0, stream>>>(Ab, Wob, out);
}